// Round 5
// baseline (77.672 us; speedup 1.0000x reference)
//
#include <hip/hip_runtime.h>

// AdaptiveRankingLoss, N=8192, fp32 in / scalar fp32 out.
// mean over pairs (i<j, t_i!=t_j) of hinge(margin - sign(tdiff)*pdiff)/(1+u_i+u_j).
//
// R4 -> R5:
//  * inner loop has NO memory ops: each wave owns a 64x64 tile; j-operands live
//    in the wave's own lanes and are broadcast per-iteration with v_readlane
//    (constant lane index after full unroll) -> pure VALU, no LDS pipe sharing,
//    no lgkmcnt waits. R4's ds_read_b128 loop shared one LDS unit per CU across
//    8 waves (~12 cyc/read issue) -- that was the suspected ~10+ us toll.
//  * pair count via __popcll(__ballot(use)): scalar-pipe s_bcnt1/s_add,
//    co-issues with VALU; removes per-lane cndmask+add from the hot loop.
//  * triangular wave-tiles: nc=128 j-chunks, 8256 tiles, 4 waves/block ->
//    2064 blocks, ~8 blocks/CU, 8 waves/SIMD.
//  * harness floor: 256 MiB d_ws re-poison at ~6.8 TB/s = ~39.4 us in the
//    timed window; only pair+finalize time is ours.

constexpr int CH  = 64;   // tile edge = wave width
constexpr int WPB = 4;    // waves (tiles) per block

__device__ __forceinline__ float bcastf(float v, int lane) {
    return __int_as_float(__builtin_amdgcn_readlane(__float_as_int(v), lane));
}

template<bool DIAG, bool EDGE>
__device__ __forceinline__ void chunk64(
    float pi, float ti, float ui1, bool ivalid,
    float tjv, float pjv, float ujv,
    int i, int j0, int n,
    float& acc, unsigned& cnt)
{
    #pragma unroll
    for (int jj = 0; jj < CH; ++jj) {
        const float tj = bcastf(tjv, jj);      // SGPR broadcasts (readlane)
        const float pj = bcastf(pjv, jj);
        const float uj = bcastf(ujv, jj);
        const float tdiff = ti - tj;
        const float pdiff = pi - pj;
        // margin/0.1 = med3(|tdiff|, 0.1, 1.0); abs is a free input modifier
        const float m3 = __builtin_amdgcn_fmed3f(fabsf(tdiff), 0.1f, 1.0f);
        // sign(tdiff)*pdiff via sign-bit xor
        const float spd = __uint_as_float(__float_as_uint(pdiff) ^
                                          (__float_as_uint(tdiff) & 0x80000000u));
        const float h = fmaxf(fmaf(m3, 0.1f, -spd), 0.0f);
        const float w = __builtin_amdgcn_rcpf(ui1 + uj);   // 1/(1+u_i+u_j)
        bool use = (tdiff != 0.0f);
        if (DIAG) use = use && ((j0 + jj) > i);
        if (EDGE) use = use && ivalid && ((j0 + jj) < n);
        acc = fmaf(use ? w : 0.0f, h, acc);
        // wave-total count on the scalar pipe; cnt is wave-uniform
        cnt += (unsigned)__popcll(__ballot(use));
    }
}

__global__ __launch_bounds__(CH * WPB) void arl_pair_kernel(
    const float* __restrict__ pred, const float* __restrict__ targ,
    const float* __restrict__ unc, int n, int nc, int nTiles,
    float2* __restrict__ partials)
{
    const int tid    = threadIdx.x;
    const int lane   = tid & 63;
    const int wid    = tid >> 6;
    const int tileId = blockIdx.x * WPB + wid;

    float acc = 0.0f;
    unsigned cnt = 0;

    if (tileId < nTiles) {
        // decode compact triangular tile id -> (r, c), c >= r
        const float nch = (float)nc + 0.5f;
        int r = (int)(nch - sqrtf(nch * nch - 2.0f * (float)tileId));
        if (r < 0) r = 0;
        if (r > nc - 1) r = nc - 1;
        auto base = [nc](int rr) { return rr * nc - (rr * (rr - 1)) / 2; };
        while (r + 1 < nc && base(r + 1) <= tileId) ++r;
        while (r > 0 && base(r) > tileId) --r;
        const int c = r + (tileId - base(r));

        const int i0 = r * CH, j0 = c * CH;
        const int i  = i0 + lane;
        const int jg = j0 + lane;
        const bool full = (i0 + CH <= n) && (j0 + CH <= n);

        if (full) {
            const float pi  = pred[i];
            const float ti  = targ[i];
            const float ui1 = 1.0f + unc[i];
            const float tjv = targ[jg];     // j-chunk lives in this wave's lanes
            const float pjv = pred[jg];
            const float ujv = unc[jg];
            if (r == c) chunk64<true , false>(pi, ti, ui1, true, tjv, pjv, ujv, i, j0, n, acc, cnt);
            else        chunk64<false, false>(pi, ti, ui1, true, tjv, pjv, ujv, i, j0, n, acc, cnt);
        } else {
            const bool iv = i < n, jv = jg < n;
            const float pi  = iv ? pred[i] : 0.0f;
            const float ti  = iv ? targ[i] : 0.0f;
            const float ui1 = 1.0f + (iv ? unc[i] : 0.0f);
            const float tjv = jv ? targ[jg] : 0.0f;
            const float pjv = jv ? pred[jg] : 0.0f;
            const float ujv = jv ? unc[jg] : 0.0f;
            if (r == c) chunk64<true , true >(pi, ti, ui1, iv, tjv, pjv, ujv, i, j0, n, acc, cnt);
            else        chunk64<false, true >(pi, ti, ui1, iv, tjv, pjv, ujv, i, j0, n, acc, cnt);
        }
    }

    // reduce: acc across lanes (cnt is already wave-uniform)
    for (int off = 32; off > 0; off >>= 1) acc += __shfl_down(acc, off);

    __shared__ float sa[WPB], sc[WPB];
    if (lane == 0) { sa[wid] = acc; sc[wid] = (float)cnt; }   // cnt <= 4096/wave-tile
    __syncthreads();
    if (tid == 0) {
        float a2 = 0.0f, c2 = 0.0f;
        #pragma unroll
        for (int w = 0; w < WPB; ++w) { a2 += sa[w]; c2 += sc[w]; }
        partials[blockIdx.x] = float2{a2, c2};   // c2 <= 16384, exact fp32
    }
}

__global__ __launch_bounds__(256) void arl_finalize(
    const float2* __restrict__ partials, int nPartials, float* __restrict__ out)
{
    float a = 0.0f, c = 0.0f;
    for (int k = threadIdx.x; k < nPartials; k += 256) {
        const float2 v = partials[k];
        a += v.x; c += v.y;
    }
    for (int off = 32; off > 0; off >>= 1) {
        a += __shfl_down(a, off);
        c += __shfl_down(c, off);
    }
    __shared__ float sa[4], sc[4];
    const int lane = threadIdx.x & 63, wid = threadIdx.x >> 6;
    if (lane == 0) { sa[wid] = a; sc[wid] = c; }
    __syncthreads();
    if (threadIdx.x == 0) {
        double A = 0.0, C = 0.0;
        #pragma unroll
        for (int w = 0; w < 4; ++w) { A += (double)sa[w]; C += (double)sc[w]; }
        out[0] = (float)(A / (C > 0.0 ? C : 1.0));
    }
}

extern "C" void kernel_launch(void* const* d_in, const int* in_sizes, int n_in,
                              void* d_out, int out_size, void* d_ws, size_t ws_size,
                              hipStream_t stream) {
    const float* pred = (const float*)d_in[0];
    const float* targ = (const float*)d_in[1];
    const float* unc  = (const float*)d_in[2];
    const int n = in_sizes[0];

    const int nc     = (n + CH - 1) / CH;        // 128 for n=8192
    const int nTiles = nc * (nc + 1) / 2;        // 8256
    const int nBlocks = (nTiles + WPB - 1) / WPB; // 2064

    float2* partials = (float2*)d_ws;            // nBlocks float2, all written

    arl_pair_kernel<<<nBlocks, CH * WPB, 0, stream>>>(pred, targ, unc, n, nc,
                                                      nTiles, partials);
    arl_finalize<<<1, 256, 0, stream>>>(partials, nBlocks, (float*)d_out);
}